// Round 5
// 8715.646 us; speedup vs baseline: 1.2740x; 1.2740x over previous
//
#include <hip/hip_runtime.h>
#include <hip/hip_bf16.h>

// ---- fixed sizes ----
#define B_SZ   64
#define T_SEQ  512
#define HID    1024
#define G4     4096

typedef __attribute__((ext_vector_type(8))) short  short8;   // 8 x bf16
typedef __attribute__((ext_vector_type(4))) float  floatx4;

#define DEV __device__ __forceinline__

DEV unsigned short f2bf(float f) {          // RNE fp32 -> bf16
  unsigned int u = __float_as_uint(f);
  u += 0x7fffu + ((u >> 16) & 1u);
  return (unsigned short)(u >> 16);
}
DEV float bf2f(unsigned short b) { return __uint_as_float(((unsigned)b) << 16); }
DEV float sigm(float x) { return 1.0f / (1.0f + __expf(-x)); }
DEV float tanh_(float x) { float e = __expf(2.0f * x); return 1.0f - 2.0f / (e + 1.0f); }

// ---------- prep: W [K][N] fp32 -> WT_hi/[lo] [N][K] bf16 ----------
__global__ __launch_bounds__(256) void transpose_cast_kernel(
    const float* __restrict__ W, unsigned short* __restrict__ WTh,
    unsigned short* __restrict__ WTl, int K, int N) {
  __shared__ float tile[32][33];
  int tx = threadIdx.x & 31, ty = threadIdx.x >> 5;
  int n0 = blockIdx.x * 32, k0 = blockIdx.y * 32;
#pragma unroll
  for (int j = 0; j < 4; j++)
    tile[ty + j * 8][tx] = W[(long)(k0 + ty + j * 8) * N + n0 + tx];
  __syncthreads();
#pragma unroll
  for (int j = 0; j < 4; j++) {
    float v = tile[tx][ty + j * 8];
    unsigned short hi = f2bf(v);
    long o = (long)(n0 + ty + j * 8) * K + k0 + tx;
    WTh[o] = hi;
    if (WTl) WTl[o] = f2bf(v - bf2f(hi));
  }
}

// ---------- prep: copy h_0 (fp32) into each layer's comm slot 1 ----------
__global__ void init_h_kernel(const float* __restrict__ h0, float* Hc0, float* Hc1) {
  int i = blockIdx.x * 256 + threadIdx.x;   // [0, 131072) = [2][64][1024]
  int l = i >> 16, j = i & 65535;
  (l ? Hc1 : Hc0)[65536 + j] = h0[i];       // slot 1
}

// ---------- cooperative LSTM layer ----------
// grid 256 = mg(4 batch groups of 16) x nb(64 col groups of 16 h-cols).
// Round-5 protocol (passing): NO fences; all cross-block traffic (h comm,
// flags) uses agent-scope RELAXED atomics = coherent bypass ops completing at
// L3. Ordering: __syncthreads drains each wave's vmcnt (h stores reach L3)
// before tid0's flag store; consumer h loads are control-dependent on the
// flag poll and never allocate in L1/L2. Per-wave waits: wave w's k-slice
// needs only producers [16w,16w+16). Xout alias write sits after the
// post-sPart __syncthreads, where all 64 flags have been observed.
//
// LOAD-WIDTH HISTORY (do NOT retry wide asm): rounds 6-9 replaced phase-3's
// 64 scalar atomic dword loads with inline-asm global_load_dwordx4 (tried
// sc0 sc1 AND sc1 alone, split and fused blocks) — ALL failed with identical
// absmax 0.402: consumed h was always the initial zeros. Conclusion: 128-bit
// loads do not honor coherent-bypass on gfx950; they allocate normally in
// L1/L2, and producer stores from other XCDs never invalidate those lines ->
// permanent stale zero hits. Coherent behavior is only reliable at native
// atomic widths (<=64-bit). Round-10 therefore widens the proven mechanism
// instead: __hip_atomic_load on unsigned long long (AGENT, RELAXED) -> one
// coherent global_load_dwordx2 per 2 floats. 32 loads/lane instead of 64,
// same bit-exact values, zero inline asm.
template <int XKI, int HILO>     // XK = XKI*128 (L0: 4 -> 512, L1: 8 -> 1024)
__global__ __launch_bounds__(256, 1) void lstm_rec(
    const float* Xsrc,                        // rows (b*512+t)*XK fp32 (aliases Xout in L1!)
    const unsigned short* __restrict__ WTh,   // [4096][XK] bf16 (hi)
    const unsigned short* __restrict__ WTl,   // [4096][XK] bf16 (lo, HILO only)
    const unsigned short* __restrict__ UT,    // [4096][1024] bf16
    float* Hc,                                // [2 slot][64][1024] fp32 comm (bypass-only)
    const float* __restrict__ bias,           // [4096]
    const float* __restrict__ c0,             // [64][1024]
    float* Xout,                              // [64][512][1024] fp32 (delayed write)
    float* hfin, float* cfin,                 // layer-1 only (else null)
    unsigned int* flags) {                    // [4 mg][64] step counters (bypass-only)
  constexpr int XK = XKI * 128;
  __shared__ __align__(16) unsigned short sU[64 * 129 * 8];  // [p][129 chunks][8], chunk 128 = pad
  __shared__ float sPart[4 * 16 * 68];                       // [wave][16 rows][68]

  const int tid = threadIdx.x;
  const int lane = tid & 63, wave = tid >> 6;
  const int quad = lane >> 4, l15 = lane & 15;
  const int nb = (int)blockIdx.x & 63, mg = (int)blockIdx.x >> 6;
  const int b0 = mg * 16;
  unsigned int* fl = flags + mg * 64;

  // stage U slice -> LDS: chunk (p, c) = UT[gcol(p)][c*8 .. c*8+7]
  for (int idx = tid; idx < 64 * 128; idx += 256) {
    int p = idx >> 7, c = idx & 127;
    int gcol = (p >> 4) * HID + nb * 16 + (p & 15);
    *(floatx4*)(sU + (p * 129 + c) * 8) =
        *(const floatx4*)(UT + (size_t)gcol * HID + (size_t)c * 8);
  }

  // W slice -> registers (B-frag layout: lane's col = its own l15)
  short8 wh[4][XKI];
  short8 wl[HILO ? 4 : 1][HILO ? XKI : 1];
#pragma unroll
  for (int nt = 0; nt < 4; nt++)
#pragma unroll
    for (int kki = 0; kki < XKI; kki++) {
      size_t o = (size_t)(nt * HID + nb * 16 + l15) * XK + wave * (XK / 4) + kki * 32 + quad * 8;
      wh[nt][kki] = *(const short8*)(WTh + o);
      if (HILO) wl[nt][kki] = *(const short8*)(WTl + o);
    }

  const int bl = tid >> 4, ii = tid & 15;
  const int bglob = b0 + bl, hcol = nb * 16 + ii;
  float c_reg = c0[bglob * HID + hcol];
  float b4[4];
#pragma unroll
  for (int g = 0; g < 4; g++) b4[g] = bias[g * HID + hcol];
  const long xout_base = ((long)bglob * T_SEQ) * HID + hcol;
  const int arow = b0 + l15;                      // A-frag row (batch) for this lane
  const float* xrow_base = Xsrc + (size_t)arow * T_SEQ * XK;
  const int fidx = wave * 16 + l15;               // this wave's producer set
  float xo_val = 0.f;
  __syncthreads();

  for (int t = 0; t < T_SEQ; t++) {
    floatx4 acc[4];
#pragma unroll
    for (int nt = 0; nt < 4; nt++) acc[nt] = floatx4{0.f, 0.f, 0.f, 0.f};

    // ---- phase 1: x @ W (independent of h; overlaps the flag wait) ----
    const float* xrow = xrow_base + (size_t)t * XK;
#pragma unroll
    for (int kki = 0; kki < XKI; kki++) {
      int kb = wave * (XK / 4) + kki * 32 + quad * 8;
      floatx4 xa = *(const floatx4*)(xrow + kb);
      floatx4 xb = *(const floatx4*)(xrow + kb + 4);
      float xs[8] = {xa[0], xa[1], xa[2], xa[3], xb[0], xb[1], xb[2], xb[3]};
      short8 ah, al;
#pragma unroll
      for (int j = 0; j < 8; j++) {
        unsigned short hi = f2bf(xs[j]);
        ah[j] = (short)hi;
        if (HILO) al[j] = (short)f2bf(xs[j] - bf2f(hi));
      }
#pragma unroll
      for (int nt = 0; nt < 4; nt++) {
        acc[nt] = __builtin_amdgcn_mfma_f32_16x16x32_bf16(ah, wh[nt][kki], acc[nt], 0, 0, 0);
        if (HILO) {
          acc[nt] = __builtin_amdgcn_mfma_f32_16x16x32_bf16(ah, wl[nt][kki], acc[nt], 0, 0, 0);
          acc[nt] = __builtin_amdgcn_mfma_f32_16x16x32_bf16(al, wh[nt][kki], acc[nt], 0, 0, 0);
        }
      }
    }

    // ---- phase 2: per-wave wait for this wave's 16 producers (step t-1) ----
    if (t > 0) {
      for (;;) {
        unsigned v = __hip_atomic_load(fl + fidx, __ATOMIC_RELAXED,
                                       __HIP_MEMORY_SCOPE_AGENT);
        if (__ballot(v >= (unsigned)t) == ~0ull) break;
        __builtin_amdgcn_s_sleep(1);
      }
      __asm__ __volatile__("" ::: "memory");   // compiler barrier only
    }

    // ---- phase 3: h @ U — 8-byte coherent atomic loads (native width) ----
    // Same addresses/values as the scalar version; each ull = 2 adjacent
    // floats (little-endian: low dword = lower address). Halves the L3
    // request count vs scalar dwords. hi/lo split stays in-register.
    const float* hrow = Hc + (size_t)((t - 1) & 1) * 65536 + (size_t)arow * HID;
#pragma unroll
    for (int kki = 0; kki < 8; kki++) {
      int kb = wave * 256 + kki * 32 + quad * 8;
      const unsigned long long* hp = (const unsigned long long*)(hrow + kb);
      float hs[8];
#pragma unroll
      for (int j = 0; j < 4; j++) {
        unsigned long long v8 = __hip_atomic_load(hp + j, __ATOMIC_RELAXED,
                                                  __HIP_MEMORY_SCOPE_AGENT);
        hs[2 * j]     = __uint_as_float((unsigned)(v8 & 0xffffffffu));
        hs[2 * j + 1] = __uint_as_float((unsigned)(v8 >> 32));
      }
      short8 hh, hl;
#pragma unroll
      for (int j = 0; j < 8; j++) {
        unsigned short hi = f2bf(hs[j]);
        hh[j] = (short)hi;
        hl[j] = (short)f2bf(hs[j] - bf2f(hi));
      }
      int q = kb >> 3;
#pragma unroll
      for (int nt = 0; nt < 4; nt++) {
        int p = nt * 16 + l15;
        short8 bfr = *(const short8*)(sU + (p * 129 + q) * 8);
        acc[nt] = __builtin_amdgcn_mfma_f32_16x16x32_bf16(hh, bfr, acc[nt], 0, 0, 0);
        acc[nt] = __builtin_amdgcn_mfma_f32_16x16x32_bf16(hl, bfr, acc[nt], 0, 0, 0);
      }
    }

    // ---- phase 4: cross-wave k-reduce via LDS ----
#pragma unroll
    for (int nt = 0; nt < 4; nt++)
#pragma unroll
      for (int r = 0; r < 4; r++)
        sPart[(wave * 16 + quad * 4 + r) * 68 + nt * 16 + l15] = acc[nt][r];
    __syncthreads();
    // all 4 waves passed their spins -> all 64 flags >= t observed -> the
    // delayed Xout write (row t-1) is race-free even in the aliased L1 case.
    if (t > 0) Xout[xout_base + (long)(t - 1) * HID] = xo_val;

    float g4[4];
#pragma unroll
    for (int g = 0; g < 4; g++) {
      int col = g * 16 + ii;
      g4[g] = sPart[(0 * 16 + bl) * 68 + col] + sPart[(1 * 16 + bl) * 68 + col] +
              sPart[(2 * 16 + bl) * 68 + col] + sPart[(3 * 16 + bl) * 68 + col] + b4[g];
    }

    // ---- phase 5: pointwise ----
    float ig = sigm(g4[0]), fg = sigm(g4[1]), gg = tanh_(g4[2]), og = sigm(g4[3]);
    c_reg = fg * c_reg + ig * gg;
    float h = og * tanh_(c_reg);
    xo_val = h;

    // ---- phase 6: publish h (bypass store, completes at L3) ----
    __hip_atomic_store(Hc + (size_t)(t & 1) * 65536 + bglob * HID + hcol, h,
                       __ATOMIC_RELAXED, __HIP_MEMORY_SCOPE_AGENT);

    // ---- phase 7: arrive. __syncthreads drains every wave's vmcnt (h
    //      stores acked at L3), then the flag store publishes step t. ----
    __syncthreads();
    if (tid == 0)
      __hip_atomic_store(fl + nb, (unsigned)(t + 1), __ATOMIC_RELAXED,
                         __HIP_MEMORY_SCOPE_AGENT);
  }

  Xout[xout_base + (long)(T_SEQ - 1) * HID] = xo_val;
  if (hfin) {
    hfin[bglob * HID + hcol] = xo_val;
    cfin[bglob * HID + hcol] = c_reg;
  }
}

// ---------------- launch ----------------
extern "C" void kernel_launch(void* const* d_in, const int* in_sizes, int n_in,
                              void* d_out, int out_size, void* d_ws, size_t ws_size,
                              hipStream_t stream) {
  const float* X  = (const float*)d_in[0];
  const float* h0 = (const float*)d_in[1];
  const float* c0 = (const float*)d_in[2];
  const float* W0 = (const float*)d_in[3];
  const float* U0 = (const float*)d_in[4];
  const float* b0 = (const float*)d_in[5];
  const float* W1 = (const float*)d_in[6];
  const float* U1 = (const float*)d_in[7];
  const float* b1 = (const float*)d_in[8];
  float* out = (float*)d_out;

  // workspace: ~33 MB + flags
  char* ws = (char*)d_ws;
  unsigned short* W0Th = (unsigned short*)(ws);                // 4 MB  [4096][512]
  unsigned short* W0Tl = (unsigned short*)(ws + (4L << 20));   // 4 MB
  unsigned short* U0T  = (unsigned short*)(ws + (8L << 20));   // 8 MB  [4096][1024]
  unsigned short* W1T  = (unsigned short*)(ws + (16L << 20));  // 8 MB
  unsigned short* U1T  = (unsigned short*)(ws + (24L << 20));  // 8 MB
  float* Hc0 = (float*)(ws + (32L << 20));                     // 512 KB [2][64][1024]
  float* Hc1 = (float*)(ws + (32L << 20) + (512L << 10));      // 512 KB
  unsigned int* fl0 = (unsigned int*)(ws + (33L << 20));       // 1 KB [4][64]
  unsigned int* fl1 = (unsigned int*)(ws + (33L << 20) + 1024);// 1 KB

  hipMemsetAsync(fl0, 0, 2048, stream);
  transpose_cast_kernel<<<dim3(128, 16), 256, 0, stream>>>(W0, W0Th, W0Tl, 512, G4);
  transpose_cast_kernel<<<dim3(128, 32), 256, 0, stream>>>(U0, U0T, nullptr, HID, G4);
  transpose_cast_kernel<<<dim3(128, 32), 256, 0, stream>>>(W1, W1T, nullptr, HID, G4);
  transpose_cast_kernel<<<dim3(128, 32), 256, 0, stream>>>(U1, U1T, nullptr, HID, G4);
  init_h_kernel<<<512, 256, 0, stream>>>(h0, Hc0, Hc1);

  {  // layer 0: x = input X; h-history -> d_out x-region (fp32)
    const float* Xs = X;
    const unsigned short* wth = W0Th; const unsigned short* wtl = W0Tl;
    const unsigned short* ut = U0T;
    float* hc = Hc0; const float* bi = b0; const float* cc = c0;
    float* xo = out; float* hf = nullptr; float* cf = nullptr;
    unsigned int* fp = fl0;
    void* a[] = {&Xs, &wth, &wtl, &ut, &hc, &bi, &cc, &xo, &hf, &cf, &fp};
    hipLaunchCooperativeKernel(reinterpret_cast<void*>(lstm_rec<4, 1>),
                               dim3(256), dim3(256), a, 0, stream);
  }
  {  // layer 1: x = layer-0 history in d_out (aliases Xout; delayed writes)
    const float* Xs = out;
    const unsigned short* wth = W1T; const unsigned short* wtl = W1T;
    const unsigned short* ut = U1T;
    float* hc = Hc1; const float* bi = b1; const float* cc = c0 + 65536;
    float* xo = out; float* hf = out + 33554432; float* cf = out + 33619968;
    unsigned int* fp = fl1;
    void* a[] = {&Xs, &wth, &wtl, &ut, &hc, &bi, &cc, &xo, &hf, &cf, &fp};
    hipLaunchCooperativeKernel(reinterpret_cast<void*>(lstm_rec<8, 0>),
                               dim3(256), dim3(256), a, 0, stream);
  }
}

// Round 7
// 7601.731 us; speedup vs baseline: 1.4607x; 1.1465x over previous
//
#include <hip/hip_runtime.h>
#include <hip/hip_bf16.h>

// ---- fixed sizes ----
#define B_SZ   64
#define T_SEQ  512
#define HID    1024
#define G4     4096

typedef __attribute__((ext_vector_type(8))) short  short8;   // 8 x bf16
typedef __attribute__((ext_vector_type(4))) float  floatx4;

#define DEV __device__ __forceinline__

DEV unsigned short f2bf(float f) {          // RNE fp32 -> bf16 (prep kernels)
  unsigned int u = __float_as_uint(f);
  u += 0x7fffu + ((u >> 16) & 1u);
  return (unsigned short)(u >> 16);
}
DEV float bf2f(unsigned short b) { return __uint_as_float(((unsigned)b) << 16); }
DEV float sigm(float x) { return 1.0f / (1.0f + __expf(-x)); }
DEV float tanh_(float x) { float e = __expf(2.0f * x); return 1.0f - 2.0f / (e + 1.0f); }

// packed fp32x2 -> bf16x2 (1 VALU op; lo16 = src0, hi16 = src1). No builtin
// on gfx950 -> inline asm. Register-only, pure -> safe for CSE/scheduling.
DEV unsigned cvtpk(float a, float b) {
  unsigned r;
  asm("v_cvt_pk_bf16_f32 %0, %1, %2" : "=v"(r) : "v"(a), "v"(b));
  return r;
}
DEV short8 pk4(unsigned a, unsigned b, unsigned c, unsigned d) {
  union { unsigned u[4]; short8 s; } x;
  x.u[0] = a; x.u[1] = b; x.u[2] = c; x.u[3] = d;
  return x.s;
}
DEV float blo(unsigned u) { return __uint_as_float(u << 16); }          // bf2f(lo16)
DEV float bhi(unsigned u) { return __uint_as_float(u & 0xffff0000u); }  // bf2f(hi16)

// ---------- prep: W [K][N] fp32 -> WT_hi/[lo] [N][K] bf16 ----------
__global__ __launch_bounds__(256) void transpose_cast_kernel(
    const float* __restrict__ W, unsigned short* __restrict__ WTh,
    unsigned short* __restrict__ WTl, int K, int N) {
  __shared__ float tile[32][33];
  int tx = threadIdx.x & 31, ty = threadIdx.x >> 5;
  int n0 = blockIdx.x * 32, k0 = blockIdx.y * 32;
#pragma unroll
  for (int j = 0; j < 4; j++)
    tile[ty + j * 8][tx] = W[(long)(k0 + ty + j * 8) * N + n0 + tx];
  __syncthreads();
#pragma unroll
  for (int j = 0; j < 4; j++) {
    float v = tile[tx][ty + j * 8];
    unsigned short hi = f2bf(v);
    long o = (long)(n0 + ty + j * 8) * K + k0 + tx;
    WTh[o] = hi;
    if (WTl) WTl[o] = f2bf(v - bf2f(hi));
  }
}

// ---------- prep: copy h_0 (fp32) into each layer's comm slot 1 ----------
__global__ void init_h_kernel(const float* __restrict__ h0, float* Hc0, float* Hc1) {
  int i = blockIdx.x * 256 + threadIdx.x;   // [0, 131072) = [2][64][1024]
  int l = i >> 16, j = i & 65535;
  (l ? Hc1 : Hc0)[65536 + j] = h0[i];       // slot 1
}

// ---------- cooperative LSTM layer ----------
// grid 256 = mg(4 batch groups of 16) x nb(64 col groups of 16 h-cols).
// Protocol (passing): NO fences; all cross-block traffic (h comm, flags)
// uses agent-scope RELAXED atomics = coherent bypass ops completing at L3.
// Ordering: __syncthreads drains each wave's vmcnt (h stores reach L3)
// before tid0's flag store; consumer h loads are control-dependent on the
// flag poll and never allocate in L1/L2.
//
// h-LOAD HISTORY (hard-won, do NOT regress):
//  * inline-asm global_load_dwordx4 (any sc bits): FAILS — 128-bit loads do
//    not honor coherent-bypass; stale zeros forever.
//  * __hip_atomic_load ull (AGENT, RELAXED) -> coherent global_load_dwordx2:
//    PROVEN (rounds 5/10).
//  * batching ALL 32 atomic loads detached ~2us from their uses (64 VGPRs of
//    in-flight results live across phase 1): FAILS with the same stale
//    signature (round 11; mechanism not fully identified — likely allocator/
//    scratch interaction with in-flight coherent loads). RULE: issue small
//    batches, consume nearby (round-5 texture).
//
// Round-12 changes (on the passing round-10 base):
//  1. cvt_pk: all fp32->bf16 hi/lo fragment construction uses
//     v_cvt_pk_bf16_f32 (2 floats/op, output IS the short8 dword layout).
//     ~80 -> 24 VALU per 8 floats; split identity x ~ hi + lo preserved.
//  2. depth-2 pipeline in phase 3: issue batch b+1's 4 atomic loads before
//     unpacking batch b (<=8 loads in flight, +16 VGPR, consume adjacent).
template <int XKI, int HILO>     // XK = XKI*128 (L0: 4 -> 512, L1: 8 -> 1024)
__global__ __launch_bounds__(256, 1) void lstm_rec(
    const float* Xsrc,                        // rows (b*512+t)*XK fp32 (aliases Xout in L1!)
    const unsigned short* __restrict__ WTh,   // [4096][XK] bf16 (hi)
    const unsigned short* __restrict__ WTl,   // [4096][XK] bf16 (lo, HILO only)
    const unsigned short* __restrict__ UT,    // [4096][1024] bf16
    float* Hc,                                // [2 slot][64][1024] fp32 comm (bypass-only)
    const float* __restrict__ bias,           // [4096]
    const float* __restrict__ c0,             // [64][1024]
    float* Xout,                              // [64][512][1024] fp32 (delayed write)
    float* hfin, float* cfin,                 // layer-1 only (else null)
    unsigned int* flags) {                    // [4 mg][64] step counters (bypass-only)
  constexpr int XK = XKI * 128;
  __shared__ __align__(16) unsigned short sU[64 * 129 * 8];  // [p][129 chunks][8], chunk 128 = pad
  __shared__ float sPart[4 * 16 * 68];                       // [wave][16 rows][68]

  const int tid = threadIdx.x;
  const int lane = tid & 63, wave = tid >> 6;
  const int quad = lane >> 4, l15 = lane & 15;
  const int nb = (int)blockIdx.x & 63, mg = (int)blockIdx.x >> 6;
  const int b0 = mg * 16;
  unsigned int* fl = flags + mg * 64;

  // stage U slice -> LDS: chunk (p, c) = UT[gcol(p)][c*8 .. c*8+7]
  for (int idx = tid; idx < 64 * 128; idx += 256) {
    int p = idx >> 7, c = idx & 127;
    int gcol = (p >> 4) * HID + nb * 16 + (p & 15);
    *(floatx4*)(sU + (p * 129 + c) * 8) =
        *(const floatx4*)(UT + (size_t)gcol * HID + (size_t)c * 8);
  }

  // W slice -> registers (B-frag layout: lane's col = its own l15)
  short8 wh[4][XKI];
  short8 wl[HILO ? 4 : 1][HILO ? XKI : 1];
#pragma unroll
  for (int nt = 0; nt < 4; nt++)
#pragma unroll
    for (int kki = 0; kki < XKI; kki++) {
      size_t o = (size_t)(nt * HID + nb * 16 + l15) * XK + wave * (XK / 4) + kki * 32 + quad * 8;
      wh[nt][kki] = *(const short8*)(WTh + o);
      if (HILO) wl[nt][kki] = *(const short8*)(WTl + o);
    }

  const int bl = tid >> 4, ii = tid & 15;
  const int bglob = b0 + bl, hcol = nb * 16 + ii;
  float c_reg = c0[bglob * HID + hcol];
  float b4[4];
#pragma unroll
  for (int g = 0; g < 4; g++) b4[g] = bias[g * HID + hcol];
  const long xout_base = ((long)bglob * T_SEQ) * HID + hcol;
  const int arow = b0 + l15;                      // A-frag row (batch) for this lane
  const float* xrow_base = Xsrc + (size_t)arow * T_SEQ * XK;
  const int fidx = wave * 16 + l15;               // this wave's producer set
  float xo_val = 0.f;
  __syncthreads();

  for (int t = 0; t < T_SEQ; t++) {
    floatx4 acc[4];
#pragma unroll
    for (int nt = 0; nt < 4; nt++) acc[nt] = floatx4{0.f, 0.f, 0.f, 0.f};

    // ---- phase 1: x @ W (independent of h; overlaps the flag wait) ----
    const float* xrow = xrow_base + (size_t)t * XK;
#pragma unroll
    for (int kki = 0; kki < XKI; kki++) {
      int kb = wave * (XK / 4) + kki * 32 + quad * 8;
      floatx4 xa = *(const floatx4*)(xrow + kb);
      floatx4 xb = *(const floatx4*)(xrow + kb + 4);
      unsigned a0 = cvtpk(xa[0], xa[1]), a1 = cvtpk(xa[2], xa[3]);
      unsigned a2 = cvtpk(xb[0], xb[1]), a3 = cvtpk(xb[2], xb[3]);
      short8 ah = pk4(a0, a1, a2, a3);
      short8 al;
      if (HILO) {
        float r0 = xa[0] - blo(a0), r1 = xa[1] - bhi(a0);
        float r2 = xa[2] - blo(a1), r3 = xa[3] - bhi(a1);
        float r4 = xb[0] - blo(a2), r5 = xb[1] - bhi(a2);
        float r6 = xb[2] - blo(a3), r7 = xb[3] - bhi(a3);
        al = pk4(cvtpk(r0, r1), cvtpk(r2, r3), cvtpk(r4, r5), cvtpk(r6, r7));
      }
#pragma unroll
      for (int nt = 0; nt < 4; nt++) {
        acc[nt] = __builtin_amdgcn_mfma_f32_16x16x32_bf16(ah, wh[nt][kki], acc[nt], 0, 0, 0);
        if (HILO) {
          acc[nt] = __builtin_amdgcn_mfma_f32_16x16x32_bf16(ah, wl[nt][kki], acc[nt], 0, 0, 0);
          acc[nt] = __builtin_amdgcn_mfma_f32_16x16x32_bf16(al, wh[nt][kki], acc[nt], 0, 0, 0);
        }
      }
    }

    // ---- phase 2: per-wave wait for this wave's 16 producers (step t-1) ----
    if (t > 0) {
      for (;;) {
        unsigned v = __hip_atomic_load(fl + fidx, __ATOMIC_RELAXED,
                                       __HIP_MEMORY_SCOPE_AGENT);
        if (__ballot(v >= (unsigned)t) == ~0ull) break;
        __builtin_amdgcn_s_sleep(1);
      }
      __asm__ __volatile__("" ::: "memory");   // compiler barrier only
    }

    // ---- phase 3: h @ U — coherent 8B atomic loads, depth-2 pipeline ----
    // Batch b = 4 x dwordx2 covering floats [wave*256 + b*32 + quad*8, +8).
    // Issue batch b+1 before consuming batch b: <=8 loads in flight, the
    // next batch's L3 latency hides under this batch's cvt+MFMA work.
    const float* hrow = Hc + (size_t)((t - 1) & 1) * 65536 + (size_t)arow * HID;
    const unsigned long long* hb =
        (const unsigned long long*)(hrow + wave * 256 + quad * 8);
#define HLD(i) __hip_atomic_load(hb + (i), __ATOMIC_RELAXED, __HIP_MEMORY_SCOPE_AGENT)
    unsigned long long pv0 = HLD(0), pv1 = HLD(1), pv2 = HLD(2), pv3 = HLD(3);
#pragma unroll
    for (int b = 0; b < 8; b++) {
      unsigned long long nv0 = 0, nv1 = 0, nv2 = 0, nv3 = 0;
      if (b < 7) {
        nv0 = HLD((b + 1) * 16 + 0); nv1 = HLD((b + 1) * 16 + 1);
        nv2 = HLD((b + 1) * 16 + 2); nv3 = HLD((b + 1) * 16 + 3);
      }
      float f0 = __uint_as_float((unsigned)(pv0 & 0xffffffffu));
      float f1 = __uint_as_float((unsigned)(pv0 >> 32));
      float f2 = __uint_as_float((unsigned)(pv1 & 0xffffffffu));
      float f3 = __uint_as_float((unsigned)(pv1 >> 32));
      float f4 = __uint_as_float((unsigned)(pv2 & 0xffffffffu));
      float f5 = __uint_as_float((unsigned)(pv2 >> 32));
      float f6 = __uint_as_float((unsigned)(pv3 & 0xffffffffu));
      float f7 = __uint_as_float((unsigned)(pv3 >> 32));
      unsigned h0 = cvtpk(f0, f1), h1 = cvtpk(f2, f3);
      unsigned h2 = cvtpk(f4, f5), h3 = cvtpk(f6, f7);
      float r0 = f0 - blo(h0), r1 = f1 - bhi(h0);
      float r2 = f2 - blo(h1), r3 = f3 - bhi(h1);
      float r4 = f4 - blo(h2), r5 = f5 - bhi(h2);
      float r6 = f6 - blo(h3), r7 = f7 - bhi(h3);
      short8 hh = pk4(h0, h1, h2, h3);
      short8 hl = pk4(cvtpk(r0, r1), cvtpk(r2, r3), cvtpk(r4, r5), cvtpk(r6, r7));
      int q = wave * 32 + b * 4 + quad;   // = (wave*256 + b*32 + quad*8) >> 3
#pragma unroll
      for (int nt = 0; nt < 4; nt++) {
        int p = nt * 16 + l15;
        short8 bfr = *(const short8*)(sU + (p * 129 + q) * 8);
        acc[nt] = __builtin_amdgcn_mfma_f32_16x16x32_bf16(hh, bfr, acc[nt], 0, 0, 0);
        acc[nt] = __builtin_amdgcn_mfma_f32_16x16x32_bf16(hl, bfr, acc[nt], 0, 0, 0);
      }
      pv0 = nv0; pv1 = nv1; pv2 = nv2; pv3 = nv3;
    }
#undef HLD

    // ---- phase 4: cross-wave k-reduce via LDS ----
#pragma unroll
    for (int nt = 0; nt < 4; nt++)
#pragma unroll
      for (int r = 0; r < 4; r++)
        sPart[(wave * 16 + quad * 4 + r) * 68 + nt * 16 + l15] = acc[nt][r];
    __syncthreads();
    // all 4 waves passed their spins -> all 64 flags >= t observed -> the
    // delayed Xout write (row t-1) is race-free even in the aliased L1 case.
    if (t > 0) Xout[xout_base + (long)(t - 1) * HID] = xo_val;

    float g4[4];
#pragma unroll
    for (int g = 0; g < 4; g++) {
      int col = g * 16 + ii;
      g4[g] = sPart[(0 * 16 + bl) * 68 + col] + sPart[(1 * 16 + bl) * 68 + col] +
              sPart[(2 * 16 + bl) * 68 + col] + sPart[(3 * 16 + bl) * 68 + col] + b4[g];
    }

    // ---- phase 5: pointwise ----
    float ig = sigm(g4[0]), fg = sigm(g4[1]), gg = tanh_(g4[2]), og = sigm(g4[3]);
    c_reg = fg * c_reg + ig * gg;
    float h = og * tanh_(c_reg);
    xo_val = h;

    // ---- phase 6: publish h (bypass store, completes at L3) ----
    __hip_atomic_store(Hc + (size_t)(t & 1) * 65536 + bglob * HID + hcol, h,
                       __ATOMIC_RELAXED, __HIP_MEMORY_SCOPE_AGENT);

    // ---- phase 7: arrive. __syncthreads drains every wave's vmcnt (h
    //      stores acked at L3), then the flag store publishes step t. ----
    __syncthreads();
    if (tid == 0)
      __hip_atomic_store(fl + nb, (unsigned)(t + 1), __ATOMIC_RELAXED,
                         __HIP_MEMORY_SCOPE_AGENT);
  }

  Xout[xout_base + (long)(T_SEQ - 1) * HID] = xo_val;
  if (hfin) {
    hfin[bglob * HID + hcol] = xo_val;
    cfin[bglob * HID + hcol] = c_reg;
  }
}

// ---------------- launch ----------------
extern "C" void kernel_launch(void* const* d_in, const int* in_sizes, int n_in,
                              void* d_out, int out_size, void* d_ws, size_t ws_size,
                              hipStream_t stream) {
  const float* X  = (const float*)d_in[0];
  const float* h0 = (const float*)d_in[1];
  const float* c0 = (const float*)d_in[2];
  const float* W0 = (const float*)d_in[3];
  const float* U0 = (const float*)d_in[4];
  const float* b0 = (const float*)d_in[5];
  const float* W1 = (const float*)d_in[6];
  const float* U1 = (const float*)d_in[7];
  const float* b1 = (const float*)d_in[8];
  float* out = (float*)d_out;

  // workspace: ~33 MB + flags
  char* ws = (char*)d_ws;
  unsigned short* W0Th = (unsigned short*)(ws);                // 4 MB  [4096][512]
  unsigned short* W0Tl = (unsigned short*)(ws + (4L << 20));   // 4 MB
  unsigned short* U0T  = (unsigned short*)(ws + (8L << 20));   // 8 MB  [4096][1024]
  unsigned short* W1T  = (unsigned short*)(ws + (16L << 20));  // 8 MB
  unsigned short* U1T  = (unsigned short*)(ws + (24L << 20));  // 8 MB
  float* Hc0 = (float*)(ws + (32L << 20));                     // 512 KB [2][64][1024]
  float* Hc1 = (float*)(ws + (32L << 20) + (512L << 10));      // 512 KB
  unsigned int* fl0 = (unsigned int*)(ws + (33L << 20));       // 1 KB [4][64]
  unsigned int* fl1 = (unsigned int*)(ws + (33L << 20) + 1024);// 1 KB

  hipMemsetAsync(fl0, 0, 2048, stream);
  transpose_cast_kernel<<<dim3(128, 16), 256, 0, stream>>>(W0, W0Th, W0Tl, 512, G4);
  transpose_cast_kernel<<<dim3(128, 32), 256, 0, stream>>>(U0, U0T, nullptr, HID, G4);
  transpose_cast_kernel<<<dim3(128, 32), 256, 0, stream>>>(W1, W1T, nullptr, HID, G4);
  transpose_cast_kernel<<<dim3(128, 32), 256, 0, stream>>>(U1, U1T, nullptr, HID, G4);
  init_h_kernel<<<512, 256, 0, stream>>>(h0, Hc0, Hc1);

  {  // layer 0: x = input X; h-history -> d_out x-region (fp32)
    const float* Xs = X;
    const unsigned short* wth = W0Th; const unsigned short* wtl = W0Tl;
    const unsigned short* ut = U0T;
    float* hc = Hc0; const float* bi = b0; const float* cc = c0;
    float* xo = out; float* hf = nullptr; float* cf = nullptr;
    unsigned int* fp = fl0;
    void* a[] = {&Xs, &wth, &wtl, &ut, &hc, &bi, &cc, &xo, &hf, &cf, &fp};
    hipLaunchCooperativeKernel(reinterpret_cast<void*>(lstm_rec<4, 1>),
                               dim3(256), dim3(256), a, 0, stream);
  }
  {  // layer 1: x = layer-0 history in d_out (aliases Xout; delayed writes)
    const float* Xs = out;
    const unsigned short* wth = W1T; const unsigned short* wtl = W1T;
    const unsigned short* ut = U1T;
    float* hc = Hc1; const float* bi = b1; const float* cc = c0 + 65536;
    float* xo = out; float* hf = out + 33554432; float* cf = out + 33619968;
    unsigned int* fp = fl1;
    void* a[] = {&Xs, &wth, &wtl, &ut, &hc, &bi, &cc, &xo, &hf, &cf, &fp};
    hipLaunchCooperativeKernel(reinterpret_cast<void*>(lstm_rec<8, 0>),
                               dim3(256), dim3(256), a, 0, stream);
  }
}